// Round 4
// baseline (1336.165 us; speedup 1.0000x reference)
//
#include <hip/hip_runtime.h>
#include <hip/hip_bf16.h>

#define N_NODES 100000
#define N_EDGES 1600000
#define NBUCKET 1563                // ceil(100000 / 64) buckets (dst >> 6)
#define NBLK_S 391                  // sort chunks: ceil(1.6M / 4096)
#define CHUNK_E 4096                // one int4 (4 edges) per thread at 1024 threads
#define CAP 1280                    // arena capacity/bucket (mean 1024 + 8 sigma)
#define GCSTRIDE 32                 // one counter per 128B line

typedef short v8s __attribute__((ext_vector_type(8)));
typedef float v4f __attribute__((ext_vector_type(4)));

static __device__ __forceinline__ unsigned pack_bf2(float a, float b) {
    __hip_bfloat162 p = __float22bfloat162_rn(make_float2(a, b));
    return *reinterpret_cast<unsigned*>(&p);
}
static __device__ __forceinline__ float2 bf2_to_f2(unsigned u) {
    __hip_bfloat162 p = *reinterpret_cast<__hip_bfloat162*>(&u);
    return __bfloat1622float2(p);
}

// ---------- K1 (1024 thr): blocks [0,NBLK_S) = bucket scatter; rest = layer-1 GEMM tiles ----------
// Sort: edges held in registers (1 int4/thread); LDS counting sort; coalesced arena write-out.
__global__ __launch_bounds__(1024) void k1_sort_gemm(const int* __restrict__ src,
                                                     const int* __restrict__ dst,
                                                     const float* __restrict__ wgt,
                                                     const float* __restrict__ x,
                                                     const float* __restrict__ W1,
                                                     int* __restrict__ gcount,
                                                     int2* __restrict__ arena,
                                                     unsigned* __restrict__ hpre) {
    __shared__ __align__(16) int smem[18004];   // 72 KB union (sort view / gemm view)
    const int b = blockIdx.x;
    const int t = threadIdx.x;

    if (b >= NBLK_S) {
        // ---- layer-1 GEMM tile: hpre[64 nodes][64 cols bf16] = x_tile @ W1 ----
        unsigned* xs = (unsigned*)smem;              // [64][68]
        unsigned* ws = (unsigned*)smem + 64 * 68;    // [64][68]
        const int tile = b - NBLK_S;
        const int row0 = tile * 64;
        {   // stage W1: fp32 [128][64] -> ws[col] bf16 at short index k (transpose)
            const float2* g2 = (const float2*)W1;
            for (int i = t; i < 64 * 128 / 2; i += 1024) {
                const float2 v = g2[i];
                const int k = (2 * i) >> 6;
                const int c = (2 * i) & 63;
                ((short*)&ws[c * 68])[k]       = (short)(pack_bf2(v.x, 0.f) & 0xFFFF);
                ((short*)&ws[(c + 1) * 68])[k] = (short)(pack_bf2(v.y, 0.f) & 0xFFFF);
            }
        }
        {   // stage x tile: fp32 -> bf16 packed
            const float4* g = (const float4*)x;
            for (int i = t; i < 64 * 32; i += 1024) {
                const int r = i >> 5, cu = i & 31;
                const int row = row0 + r;
                uint2 v = make_uint2(0u, 0u);
                if (row < N_NODES) {
                    float4 f = g[(size_t)row * 32 + cu];
                    v.x = pack_bf2(f.x, f.y);
                    v.y = pack_bf2(f.z, f.w);
                }
                *(uint2*)&xs[r * 68 + 2 * cu] = v;
            }
        }
        __syncthreads();
        const int w = t >> 6, lane = t & 63;
        const int l15 = lane & 15, quad = lane >> 4;
        const int a  = w & 3;      // out-col group (16 cols)
        const int g_ = w >> 2;     // node group (16 nodes)
        v4f acc = (v4f){0.f, 0.f, 0.f, 0.f};
#pragma unroll
        for (int k0 = 0; k0 < 128; k0 += 32) {
            const int ku = k0 / 2 + quad * 4;
            const v8s xb = *(const v8s*)&xs[(g_ * 16 + l15) * 68 + ku];
            const v8s wa = *(const v8s*)&ws[(16 * a + l15) * 68 + ku];
            acc = __builtin_amdgcn_mfma_f32_16x16x32_bf16(wa, xb, acc, 0, 0, 0);
        }
        const int node = row0 + g_ * 16 + l15;
        if (node < N_NODES) {
            uint2 o;
            o.x = pack_bf2(acc[0], acc[1]);
            o.y = pack_bf2(acc[2], acc[3]);
            *(uint2*)&hpre[(size_t)node * 32 + 8 * a + 2 * quad] = o;
        }
        return;
    }

    // ---- sort path: LDS layout ----
    int*  hist  = smem;              // [1563]
    int*  lcur  = smem + 1563;       // [1563]
    int*  tgb   = smem + 3126;       // [1563]
    int*  pairs = smem + 4689;       // [1024]
    int*  tg    = smem + 5713;       // [4096]
    int2* ord   = (int2*)(smem + 9810); // [4096] (8B aligned)

    for (int i = t; i < NBUCKET; i += 1024) hist[i] = 0;
    __syncthreads();

    const int e0 = b * CHUNK_E;
    const int n = min(CHUNK_E, N_EDGES - e0);   // 4096, or 2560 for last block
    const int nI4 = n >> 2;                     // divisible by 4 in both cases
    const bool act = t < nI4;
    int4 sv, dv; float4 wv;
    if (act) {
        sv = ((const int4*)(src + e0))[t];
        dv = ((const int4*)(dst + e0))[t];
        wv = ((const float4*)(wgt + e0))[t];
        atomicAdd(&hist[dv.x >> 6], 1);
        atomicAdd(&hist[dv.y >> 6], 1);
        atomicAdd(&hist[dv.z >> 6], 1);
        atomicAdd(&hist[dv.w >> 6], 1);
    }
    __syncthreads();
    // pair-sum + Hillis-Steele scan (1563 bins -> 782 pairs, padded to 1024)
    {
        int a0 = 0, a1 = 0;
        if (2 * t < NBUCKET) a0 = hist[2 * t];
        if (2 * t + 1 < NBUCKET) a1 = hist[2 * t + 1];
        pairs[t] = a0 + a1;
    }
    __syncthreads();
    for (int off = 1; off < 1024; off <<= 1) {
        const int u = (t >= off) ? pairs[t - off] : 0;
        __syncthreads();
        pairs[t] += u;
        __syncthreads();
    }
    if (2 * t < NBUCKET) {
        const int a0 = hist[2 * t];
        const int a1 = (2 * t + 1 < NBUCKET) ? hist[2 * t + 1] : 0;
        const int incl = pairs[t];
        lcur[2 * t] = incl - a0 - a1;            // exclusive
        if (2 * t + 1 < NBUCKET) lcur[2 * t + 1] = incl - a1;
    }
    __syncthreads();
    for (int i = t; i < NBUCKET; i += 1024) {
        const int hv = hist[i];
        const int lb = lcur[i];
        const int grsv = (hv > 0) ? atomicAdd(&gcount[i * GCSTRIDE], hv) : 0;
        tgb[i] = i * CAP + grsv - lb;
    }
    __syncthreads();
    if (act) {
        {
            const int bk = dv.x >> 6;
            const int lp = atomicAdd(&lcur[bk], 1);
            ord[lp] = make_int2(sv.x | ((dv.x & 63) << 17), __float_as_int(wv.x));
            tg[lp] = tgb[bk] + lp;
        }
        {
            const int bk = dv.y >> 6;
            const int lp = atomicAdd(&lcur[bk], 1);
            ord[lp] = make_int2(sv.y | ((dv.y & 63) << 17), __float_as_int(wv.y));
            tg[lp] = tgb[bk] + lp;
        }
        {
            const int bk = dv.z >> 6;
            const int lp = atomicAdd(&lcur[bk], 1);
            ord[lp] = make_int2(sv.z | ((dv.z & 63) << 17), __float_as_int(wv.z));
            tg[lp] = tgb[bk] + lp;
        }
        {
            const int bk = dv.w >> 6;
            const int lp = atomicAdd(&lcur[bk], 1);
            ord[lp] = make_int2(sv.w | ((dv.w & 63) << 17), __float_as_int(wv.w));
            tg[lp] = tgb[bk] + lp;
        }
    }
    __syncthreads();
    // coalesced write-out: consecutive threads -> consecutive slots within bucket runs
    for (int i = t; i < n; i += 1024)
        arena[tg[i]] = ord[i];
}

// ---------- gather helper: one record, half-wave (32 lanes), 2 LDS f32 atomics/lane ----------
static __device__ __forceinline__ void acc_rec(float* __restrict__ accs, int2 r,
                                               unsigned hv, int li) {
    const int dl = (r.x >> 17) & 63;
    const float wt = __int_as_float(r.y);
    const float2 f = bf2_to_f2(hv);
    atomicAdd(&accs[dl * 64 + 2 * li],     wt * f.x);
    atomicAdd(&accs[dl * 64 + 2 * li + 1], wt * f.y);
}

// ---------- G: bucket gather into LDS acc; FUSE=true adds in-block gemm2 (h1 @ W2) ----------
// block = 64-node bucket, 256 thr. Half-wave (32 lanes) per record: 128B h-row, coalesced.
template<bool FUSE>
__global__ __launch_bounds__(256) void gather_fuse(const unsigned* __restrict__ hsrc, // bf162 [N][32]
                                                   const int2* __restrict__ arena,
                                                   const int* __restrict__ gcount,
                                                   const float* __restrict__ bias,
                                                   const float* __restrict__ W2,
                                                   void* __restrict__ outp) {
    __shared__ float accs[64 * 64];          // 16 KB fp32 accumulator
    extern __shared__ unsigned wsdyn[];      // [64*36] bf16 W2^T (FUSE only)
    const int b = blockIdx.x;
    const int t = threadIdx.x;
    for (int i = t; i < 4096; i += 256) accs[i] = 0.f;
    if constexpr (FUSE) {
        const float2* g2 = (const float2*)W2;
        for (int i = t; i < 2048; i += 256) {
            const float2 v = g2[i];
            const int k = (2 * i) >> 6;
            const int c = (2 * i) & 63;
            ((short*)&wsdyn[c * 36])[k]       = (short)(pack_bf2(v.x, 0.f) & 0xFFFF);
            ((short*)&wsdyn[(c + 1) * 36])[k] = (short)(pack_bf2(v.y, 0.f) & 0xFFFF);
        }
    }
    __syncthreads();
    const int cnt = gcount[b * GCSTRIDE];
    const size_t base = (size_t)b * CAP;
    const int lane = t & 63;
    const int li = lane & 31;
    int i = (t >> 6) * 2 + (lane >> 5);      // record offset 0..7 per half-wave
    for (; i + 24 < cnt; i += 32) {          // 4 records in flight per half-wave
        const int2 r0 = arena[base + i];
        const int2 r1 = arena[base + i + 8];
        const int2 r2 = arena[base + i + 16];
        const int2 r3 = arena[base + i + 24];
        const unsigned h0 = hsrc[(size_t)(r0.x & 0x1FFFF) * 32 + li];
        const unsigned h1 = hsrc[(size_t)(r1.x & 0x1FFFF) * 32 + li];
        const unsigned h2 = hsrc[(size_t)(r2.x & 0x1FFFF) * 32 + li];
        const unsigned h3 = hsrc[(size_t)(r3.x & 0x1FFFF) * 32 + li];
        acc_rec(accs, r0, h0, li);
        acc_rec(accs, r1, h1, li);
        acc_rec(accs, r2, h2, li);
        acc_rec(accs, r3, h3, li);
    }
    for (; i < cnt; i += 8) {
        const int2 r = arena[base + i];
        const unsigned h = hsrc[(size_t)(r.x & 0x1FFFF) * 32 + li];
        acc_rec(accs, r, h, li);
    }
    __syncthreads();

    if constexpr (FUSE) {
        // h1 = relu(acc + b1) -> bf16, packed into xs (overlays accs via reg staging)
        unsigned pk[8];
#pragma unroll
        for (int k = 0; k < 8; ++k) {
            const int i2 = t + k * 256;          // [0,2048): node=i2>>5, colpair=i2&31
            const int node = i2 >> 5, cp = i2 & 31;
            const float f0 = fmaxf(accs[node * 64 + 2 * cp]     + bias[2 * cp],     0.f);
            const float f1 = fmaxf(accs[node * 64 + 2 * cp + 1] + bias[2 * cp + 1], 0.f);
            pk[k] = pack_bf2(f0, f1);
        }
        __syncthreads();
        unsigned* xs = (unsigned*)accs;          // overlay: [64][36]
#pragma unroll
        for (int k = 0; k < 8; ++k) {
            const int i2 = t + k * 256;
            const int node = i2 >> 5, cp = i2 & 31;
            xs[node * 36 + cp] = pk[k];
        }
        __syncthreads();
        // in-block gemm2: hpre2[64][64] = h1_tile @ W2 (bf16 out)
        const int w = t >> 6, l15 = lane & 15, quad = lane >> 4;
        v4f a4[4];
#pragma unroll
        for (int tt = 0; tt < 4; ++tt) a4[tt] = (v4f){0.f, 0.f, 0.f, 0.f};
#pragma unroll
        for (int k0 = 0; k0 < 64; k0 += 32) {
            const int ku = k0 / 2 + quad * 4;
            const v8s xb = *(const v8s*)&xs[(w * 16 + l15) * 36 + ku];
#pragma unroll
            for (int tt = 0; tt < 4; ++tt) {
                const v8s wa = *(const v8s*)&wsdyn[(16 * tt + l15) * 36 + ku];
                a4[tt] = __builtin_amdgcn_mfma_f32_16x16x32_bf16(wa, xb, a4[tt], 0, 0, 0);
            }
        }
        const int ng = b * 64 + w * 16 + l15;
        if (ng < N_NODES) {
#pragma unroll
            for (int tt = 0; tt < 4; ++tt) {
                uint2 o;
                o.x = pack_bf2(a4[tt][0], a4[tt][1]);
                o.y = pack_bf2(a4[tt][2], a4[tt][3]);
                *(uint2*)&((unsigned*)outp)[(size_t)ng * 32 + 8 * tt + 2 * quad] = o;
            }
        }
    } else {
        // out = relu(acc + b2), fp32
        for (int i2 = t; i2 < 2048; i2 += 256) {
            const int node = i2 >> 5, cp = i2 & 31;
            const int ng = b * 64 + node;
            if (ng < N_NODES) {
                float2 o;
                o.x = fmaxf(accs[node * 64 + 2 * cp]     + bias[2 * cp],     0.f);
                o.y = fmaxf(accs[node * 64 + 2 * cp + 1] + bias[2 * cp + 1], 0.f);
                *(float2*)&((float*)outp)[(size_t)ng * 64 + 2 * cp] = o;
            }
        }
    }
}

extern "C" void kernel_launch(void* const* d_in, const int* in_sizes, int n_in,
                              void* d_out, int out_size, void* d_ws, size_t ws_size,
                              hipStream_t stream) {
    const float* x    = (const float*)d_in[0];          // [100000, 128]
    const int*   eidx = (const int*)d_in[1];            // [2, 1600000]
    const float* mask = (const float*)d_in[2];          // [1600000]
    const float* W1   = (const float*)d_in[3];          // [128, 64]
    const float* b1   = (const float*)d_in[4];          // [64]
    const float* W2   = (const float*)d_in[5];          // [64, 64]
    const float* b2   = (const float*)d_in[6];          // [64]
    float* out = (float*)d_out;                          // [100000, 64]

    const int* src = eidx;
    const int* dst = eidx + N_EDGES;

    // hpre (layer-1 pre-acts, bf16 [N][32] dwords = 12.8 MB) lives in d_out (25.6 MB),
    // dead before G2 overwrites d_out with the final fp32 output.
    unsigned* hpre = (unsigned*)d_out;

    // workspace: arena 16.0 MB | gcount 0.2 MB | hpre2 12.8 MB  (~29 MB total)
    int2*     arena  = (int2*)d_ws;
    int*      gcount = (int*)(arena + (size_t)NBUCKET * CAP);
    unsigned* hpre2  = (unsigned*)(gcount + NBUCKET * GCSTRIDE);

    const int gemmBlocks = (N_NODES + 63) / 64;          // 1563

    // zero padded bucket counters (stream-ordered, graph-capturable)
    hipMemsetAsync(gcount, 0, NBUCKET * GCSTRIDE * sizeof(int), stream);

    // K1: bucket scatter (blocks 0..390) + layer-1 GEMM tiles (blocks 391..1953)
    k1_sort_gemm<<<NBLK_S + gemmBlocks, 1024, 0, stream>>>(src, dst, mask, x, W1,
                                                           gcount, arena, hpre);

    // G1: gather layer 1 + fused gemm2 -> hpre2 (bf16)
    gather_fuse<true><<<NBUCKET, 256, 64 * 36 * 4, stream>>>(hpre, arena, gcount,
                                                             b1, W2, hpre2);
    // G2: gather layer 2 -> out (fp32)
    gather_fuse<false><<<NBUCKET, 256, 0, stream>>>(hpre2, arena, gcount,
                                                    b2, nullptr, out);
}

// Round 5
// 255.456 us; speedup vs baseline: 5.2305x; 5.2305x over previous
//
#include <hip/hip_runtime.h>
#include <hip/hip_bf16.h>

#define N_NODES 100000
#define N_EDGES 1600000
#define NBUCKET 1563                // ceil(100000 / 64) buckets (dst >> 6)
#define NBLK_S 391                  // sort chunks: ceil(1.6M / 4096)
#define CHUNK_E 4096                // one int4 (4 edges) per thread at 1024 threads
#define CAP 1280                    // arena capacity/bucket (mean 1024 + 8 sigma)
#define GCSTRIDE 32                 // one counter per 128B line
#define FIXSCALE 1048576.0f         // 2^20 fixed-point scale for LDS int accumulation
#define FIXINV   (1.0f / 1048576.0f)

typedef short v8s __attribute__((ext_vector_type(8)));
typedef float v4f __attribute__((ext_vector_type(4)));

static __device__ __forceinline__ unsigned pack_bf2(float a, float b) {
    __hip_bfloat162 p = __float22bfloat162_rn(make_float2(a, b));
    return *reinterpret_cast<unsigned*>(&p);
}
static __device__ __forceinline__ float2 bf2_to_f2(unsigned u) {
    __hip_bfloat162 p = *reinterpret_cast<__hip_bfloat162*>(&u);
    return __bfloat1622float2(p);
}

// ---------- K1 (1024 thr): blocks [0,NBLK_S) = bucket scatter; rest = layer-1 GEMM tiles ----------
// Sort: edges held in registers (1 int4/thread); LDS counting sort; coalesced arena write-out.
__global__ __launch_bounds__(1024) void k1_sort_gemm(const int* __restrict__ src,
                                                     const int* __restrict__ dst,
                                                     const float* __restrict__ wgt,
                                                     const float* __restrict__ x,
                                                     const float* __restrict__ W1,
                                                     int* __restrict__ gcount,
                                                     int2* __restrict__ arena,
                                                     unsigned* __restrict__ hpre) {
    __shared__ __align__(16) int smem[18004];   // 72 KB union (sort view / gemm view)
    const int b = blockIdx.x;
    const int t = threadIdx.x;

    if (b >= NBLK_S) {
        // ---- layer-1 GEMM tile: hpre[64 nodes][64 cols bf16] = x_tile @ W1 ----
        unsigned* xs = (unsigned*)smem;              // [64][68]
        unsigned* ws = (unsigned*)smem + 64 * 68;    // [64][68]
        const int tile = b - NBLK_S;
        const int row0 = tile * 64;
        {   // stage W1: fp32 [128][64] -> ws[col] bf16 at short index k (transpose)
            const float2* g2 = (const float2*)W1;
            for (int i = t; i < 64 * 128 / 2; i += 1024) {
                const float2 v = g2[i];
                const int k = (2 * i) >> 6;
                const int c = (2 * i) & 63;
                ((short*)&ws[c * 68])[k]       = (short)(pack_bf2(v.x, 0.f) & 0xFFFF);
                ((short*)&ws[(c + 1) * 68])[k] = (short)(pack_bf2(v.y, 0.f) & 0xFFFF);
            }
        }
        {   // stage x tile: fp32 -> bf16 packed
            const float4* g = (const float4*)x;
            for (int i = t; i < 64 * 32; i += 1024) {
                const int r = i >> 5, cu = i & 31;
                const int row = row0 + r;
                uint2 v = make_uint2(0u, 0u);
                if (row < N_NODES) {
                    float4 f = g[(size_t)row * 32 + cu];
                    v.x = pack_bf2(f.x, f.y);
                    v.y = pack_bf2(f.z, f.w);
                }
                *(uint2*)&xs[r * 68 + 2 * cu] = v;
            }
        }
        __syncthreads();
        const int w = t >> 6, lane = t & 63;
        const int l15 = lane & 15, quad = lane >> 4;
        const int a  = w & 3;      // out-col group (16 cols)
        const int g_ = w >> 2;     // node group (16 nodes)
        v4f acc = (v4f){0.f, 0.f, 0.f, 0.f};
#pragma unroll
        for (int k0 = 0; k0 < 128; k0 += 32) {
            const int ku = k0 / 2 + quad * 4;
            const v8s xb = *(const v8s*)&xs[(g_ * 16 + l15) * 68 + ku];
            const v8s wa = *(const v8s*)&ws[(16 * a + l15) * 68 + ku];
            acc = __builtin_amdgcn_mfma_f32_16x16x32_bf16(wa, xb, acc, 0, 0, 0);
        }
        const int node = row0 + g_ * 16 + l15;
        if (node < N_NODES) {
            uint2 o;
            o.x = pack_bf2(acc[0], acc[1]);
            o.y = pack_bf2(acc[2], acc[3]);
            *(uint2*)&hpre[(size_t)node * 32 + 8 * a + 2 * quad] = o;
        }
        return;
    }

    // ---- sort path: LDS layout ----
    int*  hist  = smem;              // [1563]
    int*  lcur  = smem + 1563;       // [1563]
    int*  tgb   = smem + 3126;       // [1563]
    int*  pairs = smem + 4689;       // [1024]
    int*  tg    = smem + 5713;       // [4096]
    int2* ord   = (int2*)(smem + 9810); // [4096] (8B aligned)

    for (int i = t; i < NBUCKET; i += 1024) hist[i] = 0;
    __syncthreads();

    const int e0 = b * CHUNK_E;
    const int n = min(CHUNK_E, N_EDGES - e0);   // 4096, or 2560 for last block
    const int nI4 = n >> 2;                     // divisible by 4 in both cases
    const bool act = t < nI4;
    int4 sv, dv; float4 wv;
    if (act) {
        sv = ((const int4*)(src + e0))[t];
        dv = ((const int4*)(dst + e0))[t];
        wv = ((const float4*)(wgt + e0))[t];
        atomicAdd(&hist[dv.x >> 6], 1);
        atomicAdd(&hist[dv.y >> 6], 1);
        atomicAdd(&hist[dv.z >> 6], 1);
        atomicAdd(&hist[dv.w >> 6], 1);
    }
    __syncthreads();
    // pair-sum + Hillis-Steele scan (1563 bins -> 782 pairs, padded to 1024)
    {
        int a0 = 0, a1 = 0;
        if (2 * t < NBUCKET) a0 = hist[2 * t];
        if (2 * t + 1 < NBUCKET) a1 = hist[2 * t + 1];
        pairs[t] = a0 + a1;
    }
    __syncthreads();
    for (int off = 1; off < 1024; off <<= 1) {
        const int u = (t >= off) ? pairs[t - off] : 0;
        __syncthreads();
        pairs[t] += u;
        __syncthreads();
    }
    if (2 * t < NBUCKET) {
        const int a0 = hist[2 * t];
        const int a1 = (2 * t + 1 < NBUCKET) ? hist[2 * t + 1] : 0;
        const int incl = pairs[t];
        lcur[2 * t] = incl - a0 - a1;            // exclusive
        if (2 * t + 1 < NBUCKET) lcur[2 * t + 1] = incl - a1;
    }
    __syncthreads();
    for (int i = t; i < NBUCKET; i += 1024) {
        const int hv = hist[i];
        const int lb = lcur[i];
        const int grsv = (hv > 0) ? atomicAdd(&gcount[i * GCSTRIDE], hv) : 0;
        tgb[i] = i * CAP + grsv - lb;
    }
    __syncthreads();
    if (act) {
        {
            const int bk = dv.x >> 6;
            const int lp = atomicAdd(&lcur[bk], 1);
            ord[lp] = make_int2(sv.x | ((dv.x & 63) << 17), __float_as_int(wv.x));
            tg[lp] = tgb[bk] + lp;
        }
        {
            const int bk = dv.y >> 6;
            const int lp = atomicAdd(&lcur[bk], 1);
            ord[lp] = make_int2(sv.y | ((dv.y & 63) << 17), __float_as_int(wv.y));
            tg[lp] = tgb[bk] + lp;
        }
        {
            const int bk = dv.z >> 6;
            const int lp = atomicAdd(&lcur[bk], 1);
            ord[lp] = make_int2(sv.z | ((dv.z & 63) << 17), __float_as_int(wv.z));
            tg[lp] = tgb[bk] + lp;
        }
        {
            const int bk = dv.w >> 6;
            const int lp = atomicAdd(&lcur[bk], 1);
            ord[lp] = make_int2(sv.w | ((dv.w & 63) << 17), __float_as_int(wv.w));
            tg[lp] = tgb[bk] + lp;
        }
    }
    __syncthreads();
    // coalesced write-out: consecutive threads -> consecutive slots within bucket runs
    for (int i = t; i < n; i += 1024)
        arena[tg[i]] = ord[i];
}

// ---------- gather helper: one record, half-wave (32 lanes), 2 native ds_add_u32/lane ----------
// fp32 LDS atomicAdd compiles to a CAS retry loop (no -munsafe-fp-atomics) => 16x stall.
// int LDS atomicAdd is a single native ds_add_u32; accumulate in 2^20 fixed point.
static __device__ __forceinline__ void acc_rec(int* __restrict__ accs, int2 r,
                                               unsigned hv, int li) {
    const int dl = (r.x >> 17) & 63;
    const float wt = __int_as_float(r.y);
    const float2 f = bf2_to_f2(hv);
    atomicAdd(&accs[dl * 64 + 2 * li],     (int)(wt * f.x * FIXSCALE));
    atomicAdd(&accs[dl * 64 + 2 * li + 1], (int)(wt * f.y * FIXSCALE));
}

// ---------- G: bucket gather into LDS int acc; FUSE=true adds in-block gemm2 (h1 @ W2) ----------
// block = 64-node bucket, 256 thr. Half-wave (32 lanes) per record: 128B h-row, coalesced.
template<bool FUSE>
__global__ __launch_bounds__(256) void gather_fuse(const unsigned* __restrict__ hsrc, // bf162 [N][32]
                                                   const int2* __restrict__ arena,
                                                   const int* __restrict__ gcount,
                                                   const float* __restrict__ bias,
                                                   const float* __restrict__ W2,
                                                   void* __restrict__ outp) {
    __shared__ int accs[64 * 64];            // 16 KB fixed-point accumulator
    extern __shared__ unsigned wsdyn[];      // [64*36] bf16 W2^T (FUSE only)
    const int b = blockIdx.x;
    const int t = threadIdx.x;
    for (int i = t; i < 4096; i += 256) accs[i] = 0;
    if constexpr (FUSE) {
        const float2* g2 = (const float2*)W2;
        for (int i = t; i < 2048; i += 256) {
            const float2 v = g2[i];
            const int k = (2 * i) >> 6;
            const int c = (2 * i) & 63;
            ((short*)&wsdyn[c * 36])[k]       = (short)(pack_bf2(v.x, 0.f) & 0xFFFF);
            ((short*)&wsdyn[(c + 1) * 36])[k] = (short)(pack_bf2(v.y, 0.f) & 0xFFFF);
        }
    }
    __syncthreads();
    const int cnt = gcount[b * GCSTRIDE];
    const size_t base = (size_t)b * CAP;
    const int lane = t & 63;
    const int li = lane & 31;
    int i = (t >> 6) * 2 + (lane >> 5);      // record offset 0..7 per half-wave
    for (; i + 24 < cnt; i += 32) {          // 4 records in flight per half-wave
        const int2 r0 = arena[base + i];
        const int2 r1 = arena[base + i + 8];
        const int2 r2 = arena[base + i + 16];
        const int2 r3 = arena[base + i + 24];
        const unsigned h0 = hsrc[(size_t)(r0.x & 0x1FFFF) * 32 + li];
        const unsigned h1 = hsrc[(size_t)(r1.x & 0x1FFFF) * 32 + li];
        const unsigned h2 = hsrc[(size_t)(r2.x & 0x1FFFF) * 32 + li];
        const unsigned h3 = hsrc[(size_t)(r3.x & 0x1FFFF) * 32 + li];
        acc_rec(accs, r0, h0, li);
        acc_rec(accs, r1, h1, li);
        acc_rec(accs, r2, h2, li);
        acc_rec(accs, r3, h3, li);
    }
    for (; i < cnt; i += 8) {
        const int2 r = arena[base + i];
        const unsigned h = hsrc[(size_t)(r.x & 0x1FFFF) * 32 + li];
        acc_rec(accs, r, h, li);
    }
    __syncthreads();

    if constexpr (FUSE) {
        // h1 = relu(acc*2^-20 + b1) -> bf16, packed into xs (overlays accs via reg staging)
        unsigned pk[8];
#pragma unroll
        for (int k = 0; k < 8; ++k) {
            const int i2 = t + k * 256;          // [0,2048): node=i2>>5, colpair=i2&31
            const int node = i2 >> 5, cp = i2 & 31;
            const float f0 = fmaxf((float)accs[node * 64 + 2 * cp]     * FIXINV + bias[2 * cp],     0.f);
            const float f1 = fmaxf((float)accs[node * 64 + 2 * cp + 1] * FIXINV + bias[2 * cp + 1], 0.f);
            pk[k] = pack_bf2(f0, f1);
        }
        __syncthreads();
        unsigned* xs = (unsigned*)accs;          // overlay: [64][36]
#pragma unroll
        for (int k = 0; k < 8; ++k) {
            const int i2 = t + k * 256;
            const int node = i2 >> 5, cp = i2 & 31;
            xs[node * 36 + cp] = pk[k];
        }
        __syncthreads();
        // in-block gemm2: hpre2[64][64] = h1_tile @ W2 (bf16 out)
        const int w = t >> 6, l15 = lane & 15, quad = lane >> 4;
        v4f a4[4];
#pragma unroll
        for (int tt = 0; tt < 4; ++tt) a4[tt] = (v4f){0.f, 0.f, 0.f, 0.f};
#pragma unroll
        for (int k0 = 0; k0 < 64; k0 += 32) {
            const int ku = k0 / 2 + quad * 4;
            const v8s xb = *(const v8s*)&xs[(w * 16 + l15) * 36 + ku];
#pragma unroll
            for (int tt = 0; tt < 4; ++tt) {
                const v8s wa = *(const v8s*)&wsdyn[(16 * tt + l15) * 36 + ku];
                a4[tt] = __builtin_amdgcn_mfma_f32_16x16x32_bf16(wa, xb, a4[tt], 0, 0, 0);
            }
        }
        const int ng = b * 64 + w * 16 + l15;
        if (ng < N_NODES) {
#pragma unroll
            for (int tt = 0; tt < 4; ++tt) {
                uint2 o;
                o.x = pack_bf2(a4[tt][0], a4[tt][1]);
                o.y = pack_bf2(a4[tt][2], a4[tt][3]);
                *(uint2*)&((unsigned*)outp)[(size_t)ng * 32 + 8 * tt + 2 * quad] = o;
            }
        }
    } else {
        // out = relu(acc*2^-20 + b2), fp32
        for (int i2 = t; i2 < 2048; i2 += 256) {
            const int node = i2 >> 5, cp = i2 & 31;
            const int ng = b * 64 + node;
            if (ng < N_NODES) {
                float2 o;
                o.x = fmaxf((float)accs[node * 64 + 2 * cp]     * FIXINV + bias[2 * cp],     0.f);
                o.y = fmaxf((float)accs[node * 64 + 2 * cp + 1] * FIXINV + bias[2 * cp + 1], 0.f);
                *(float2*)&((float*)outp)[(size_t)ng * 64 + 2 * cp] = o;
            }
        }
    }
}

extern "C" void kernel_launch(void* const* d_in, const int* in_sizes, int n_in,
                              void* d_out, int out_size, void* d_ws, size_t ws_size,
                              hipStream_t stream) {
    const float* x    = (const float*)d_in[0];          // [100000, 128]
    const int*   eidx = (const int*)d_in[1];            // [2, 1600000]
    const float* mask = (const float*)d_in[2];          // [1600000]
    const float* W1   = (const float*)d_in[3];          // [128, 64]
    const float* b1   = (const float*)d_in[4];          // [64]
    const float* W2   = (const float*)d_in[5];          // [64, 64]
    const float* b2   = (const float*)d_in[6];          // [64]
    float* out = (float*)d_out;                          // [100000, 64]

    const int* src = eidx;
    const int* dst = eidx + N_EDGES;

    // hpre (layer-1 pre-acts, bf16 [N][32] dwords = 12.8 MB) lives in d_out (25.6 MB),
    // dead before G2 overwrites d_out with the final fp32 output.
    unsigned* hpre = (unsigned*)d_out;

    // workspace: arena 16.0 MB | gcount 0.2 MB | hpre2 12.8 MB  (~29 MB total)
    int2*     arena  = (int2*)d_ws;
    int*      gcount = (int*)(arena + (size_t)NBUCKET * CAP);
    unsigned* hpre2  = (unsigned*)(gcount + NBUCKET * GCSTRIDE);

    const int gemmBlocks = (N_NODES + 63) / 64;          // 1563

    // zero padded bucket counters (stream-ordered, graph-capturable)
    hipMemsetAsync(gcount, 0, NBUCKET * GCSTRIDE * sizeof(int), stream);

    // K1: bucket scatter (blocks 0..390) + layer-1 GEMM tiles (blocks 391..1953)
    k1_sort_gemm<<<NBLK_S + gemmBlocks, 1024, 0, stream>>>(src, dst, mask, x, W1,
                                                           gcount, arena, hpre);

    // G1: gather layer 1 + fused gemm2 -> hpre2 (bf16)
    gather_fuse<true><<<NBUCKET, 256, 64 * 36 * 4, stream>>>(hpre, arena, gcount,
                                                             b1, W2, hpre2);
    // G2: gather layer 2 -> out (fp32)
    gather_fuse<false><<<NBUCKET, 256, 0, stream>>>(hpre2, arena, gcount,
                                                    b2, nullptr, out);
}

// Round 6
// 245.047 us; speedup vs baseline: 5.4527x; 1.0425x over previous
//
#include <hip/hip_runtime.h>
#include <hip/hip_bf16.h>

#define N_NODES 100000
#define N_EDGES 1600000
#define NBUCKET 1563                // ceil(100000 / 64) buckets (dst >> 6)
#define NBLK_S 391                  // sort chunks: ceil(1.6M / 4096)
#define CHUNK_E 4096                // one int4 (4 edges) per thread at 1024 threads
#define CAP 1280                    // arena capacity/bucket (mean 1024 + 8 sigma)
#define GCSTRIDE 32                 // one counter per 128B line
#define FIXSCALE 1048576.0f         // 2^20 fixed-point scale for LDS int accumulation
#define FIXINV   (1.0f / 1048576.0f)

// hpre/hpre2 packing: dword d of a row = bf16 pair (col d, col d+32).
// This makes gather's two ds_add instructions hit banks 0..31 with exactly
// 2 lanes/bank (free per m136) instead of 4-way on even banks.

typedef short v8s __attribute__((ext_vector_type(8)));
typedef float v4f __attribute__((ext_vector_type(4)));

static __device__ __forceinline__ unsigned pack_bf2(float a, float b) {
    __hip_bfloat162 p = __float22bfloat162_rn(make_float2(a, b));
    return *reinterpret_cast<unsigned*>(&p);
}
static __device__ __forceinline__ float2 bf2_to_f2(unsigned u) {
    __hip_bfloat162 p = *reinterpret_cast<__hip_bfloat162*>(&u);
    return __bfloat1622float2(p);
}

// ---------- K1 (1024 thr): blocks [0,NBLK_S) = bucket scatter; rest = layer-1 GEMM tiles ----------
__global__ __launch_bounds__(1024) void k1_sort_gemm(const int* __restrict__ src,
                                                     const int* __restrict__ dst,
                                                     const float* __restrict__ wgt,
                                                     const float* __restrict__ x,
                                                     const float* __restrict__ W1,
                                                     int* __restrict__ gcount,
                                                     int2* __restrict__ arena,
                                                     unsigned* __restrict__ hpre) {
    __shared__ __align__(16) int smem[18004];   // 72 KB union (sort view / gemm view)
    const int b = blockIdx.x;
    const int t = threadIdx.x;

    if (b >= NBLK_S) {
        // ---- layer-1 GEMM tile: hpre[64 nodes][32 dwords] = x_tile @ W1 (packed d,d+32) ----
        unsigned* xs = (unsigned*)smem;              // [64][68]
        unsigned* ws = (unsigned*)smem + 64 * 68;    // [64][68]
        const int tile = b - NBLK_S;
        const int row0 = tile * 64;
        {   // stage W1: fp32 [128][64] -> ws[col] bf16 at short index k (transpose)
            const float2* g2 = (const float2*)W1;
            for (int i = t; i < 64 * 128 / 2; i += 1024) {
                const float2 v = g2[i];
                const int k = (2 * i) >> 6;
                const int c = (2 * i) & 63;
                ((short*)&ws[c * 68])[k]       = (short)(pack_bf2(v.x, 0.f) & 0xFFFF);
                ((short*)&ws[(c + 1) * 68])[k] = (short)(pack_bf2(v.y, 0.f) & 0xFFFF);
            }
        }
        {   // stage x tile: fp32 -> bf16 packed
            const float4* g = (const float4*)x;
            for (int i = t; i < 64 * 32; i += 1024) {
                const int r = i >> 5, cu = i & 31;
                const int row = row0 + r;
                uint2 v = make_uint2(0u, 0u);
                if (row < N_NODES) {
                    float4 f = g[(size_t)row * 32 + cu];
                    v.x = pack_bf2(f.x, f.y);
                    v.y = pack_bf2(f.z, f.w);
                }
                *(uint2*)&xs[r * 68 + 2 * cu] = v;
            }
        }
        __syncthreads();
        const int w = t >> 6, lane = t & 63;
        const int l15 = lane & 15, quad = lane >> 4;
        const int a  = w & 3;      // out-col group (16 cols)
        const int g_ = w >> 2;     // node group (16 nodes)
        v4f acc = (v4f){0.f, 0.f, 0.f, 0.f};
#pragma unroll
        for (int k0 = 0; k0 < 128; k0 += 32) {
            const int ku = k0 / 2 + quad * 4;
            const v8s xb = *(const v8s*)&xs[(g_ * 16 + l15) * 68 + ku];
            const v8s wa = *(const v8s*)&ws[(16 * a + l15) * 68 + ku];
            acc = __builtin_amdgcn_mfma_f32_16x16x32_bf16(wa, xb, acc, 0, 0, 0);
        }
        // repack epilogue: stage fp32 tile in LDS, emit (d, d+32) bf16 pairs
        __syncthreads();                              // xs/ws dead
        float* stg = (float*)smem;                    // [64][68] fp32
        *(v4f*)&stg[(g_ * 16 + l15) * 68 + 16 * a + 4 * quad] = acc;
        __syncthreads();
        for (int i2 = t; i2 < 2048; i2 += 1024) {
            const int nl = i2 >> 5, d = i2 & 31;
            const int row = row0 + nl;
            if (row < N_NODES)
                hpre[(size_t)row * 32 + d] = pack_bf2(stg[nl * 68 + d], stg[nl * 68 + d + 32]);
        }
        return;
    }

    // ---- sort path: LDS layout ----
    int*  hist  = smem;              // [1563]
    int*  lcur  = smem + 1563;       // [1563]
    int*  tgb   = smem + 3126;       // [1563]
    int*  pairs = smem + 4689;       // [1024]
    int*  tg    = smem + 5713;       // [4096]
    int2* ord   = (int2*)(smem + 9810); // [4096] (8B aligned)

    for (int i = t; i < NBUCKET; i += 1024) hist[i] = 0;
    __syncthreads();

    const int e0 = b * CHUNK_E;
    const int n = min(CHUNK_E, N_EDGES - e0);   // 4096, or 2560 for last block
    const int nI4 = n >> 2;
    const bool act = t < nI4;
    int4 sv, dv; float4 wv;
    if (act) {
        sv = ((const int4*)(src + e0))[t];
        dv = ((const int4*)(dst + e0))[t];
        wv = ((const float4*)(wgt + e0))[t];
        atomicAdd(&hist[dv.x >> 6], 1);
        atomicAdd(&hist[dv.y >> 6], 1);
        atomicAdd(&hist[dv.z >> 6], 1);
        atomicAdd(&hist[dv.w >> 6], 1);
    }
    __syncthreads();
    {
        int a0 = 0, a1 = 0;
        if (2 * t < NBUCKET) a0 = hist[2 * t];
        if (2 * t + 1 < NBUCKET) a1 = hist[2 * t + 1];
        pairs[t] = a0 + a1;
    }
    __syncthreads();
    for (int off = 1; off < 1024; off <<= 1) {
        const int u = (t >= off) ? pairs[t - off] : 0;
        __syncthreads();
        pairs[t] += u;
        __syncthreads();
    }
    if (2 * t < NBUCKET) {
        const int a0 = hist[2 * t];
        const int a1 = (2 * t + 1 < NBUCKET) ? hist[2 * t + 1] : 0;
        const int incl = pairs[t];
        lcur[2 * t] = incl - a0 - a1;            // exclusive
        if (2 * t + 1 < NBUCKET) lcur[2 * t + 1] = incl - a1;
    }
    __syncthreads();
    for (int i = t; i < NBUCKET; i += 1024) {
        const int hv = hist[i];
        const int lb = lcur[i];
        const int grsv = (hv > 0) ? atomicAdd(&gcount[i * GCSTRIDE], hv) : 0;
        tgb[i] = i * CAP + grsv - lb;
    }
    __syncthreads();
    if (act) {
        {
            const int bk = dv.x >> 6;
            const int lp = atomicAdd(&lcur[bk], 1);
            ord[lp] = make_int2(sv.x | ((dv.x & 63) << 17), __float_as_int(wv.x));
            tg[lp] = tgb[bk] + lp;
        }
        {
            const int bk = dv.y >> 6;
            const int lp = atomicAdd(&lcur[bk], 1);
            ord[lp] = make_int2(sv.y | ((dv.y & 63) << 17), __float_as_int(wv.y));
            tg[lp] = tgb[bk] + lp;
        }
        {
            const int bk = dv.z >> 6;
            const int lp = atomicAdd(&lcur[bk], 1);
            ord[lp] = make_int2(sv.z | ((dv.z & 63) << 17), __float_as_int(wv.z));
            tg[lp] = tgb[bk] + lp;
        }
        {
            const int bk = dv.w >> 6;
            const int lp = atomicAdd(&lcur[bk], 1);
            ord[lp] = make_int2(sv.w | ((dv.w & 63) << 17), __float_as_int(wv.w));
            tg[lp] = tgb[bk] + lp;
        }
    }
    __syncthreads();
    for (int i = t; i < n; i += 1024)
        arena[tg[i]] = ord[i];
}

// ---------- gather helper: conflict-free ds_add (banks 0..31, 2 lanes/bank) ----------
static __device__ __forceinline__ void acc_rec(int* __restrict__ accs, int2 r,
                                               unsigned hv, int li) {
    const int dl = (r.x >> 17) & 63;
    const float ws = __int_as_float(r.y) * FIXSCALE;
    const float2 f = bf2_to_f2(hv);          // f.x = col li, f.y = col li+32
    atomicAdd(&accs[dl * 64 + li],      (int)(ws * f.x));
    atomicAdd(&accs[dl * 64 + 32 + li], (int)(ws * f.y));
}

// ---------- G: bucket gather into LDS int acc; FUSE=true adds in-block gemm2 (h1 @ W2) ----------
template<bool FUSE>
__global__ __launch_bounds__(256) void gather_fuse(const unsigned* __restrict__ hsrc, // packed [N][32]
                                                   const int2* __restrict__ arena,
                                                   const int* __restrict__ gcount,
                                                   const float* __restrict__ bias,
                                                   const float* __restrict__ W2,
                                                   void* __restrict__ outp) {
    __shared__ int accs[64 * 68];            // [0,4096): fixed-point acc; also fp32 staging [64][68]
    extern __shared__ unsigned wsdyn[];      // [64*36] bf16 W2^T (FUSE only)
    const int b = blockIdx.x;
    const int t = threadIdx.x;
    for (int i = t; i < 4096; i += 256) accs[i] = 0;
    if constexpr (FUSE) {
        const float2* g2 = (const float2*)W2;
        for (int i = t; i < 2048; i += 256) {
            const float2 v = g2[i];
            const int k = (2 * i) >> 6;
            const int c = (2 * i) & 63;
            ((short*)&wsdyn[c * 36])[k]       = (short)(pack_bf2(v.x, 0.f) & 0xFFFF);
            ((short*)&wsdyn[(c + 1) * 36])[k] = (short)(pack_bf2(v.y, 0.f) & 0xFFFF);
        }
    }
    __syncthreads();
    const int cnt = gcount[b * GCSTRIDE];
    const size_t base = (size_t)b * CAP;
    const int lane = t & 63;
    const int li = lane & 31;
    int i = (t >> 6) * 2 + (lane >> 5);      // record offset 0..7 per half-wave
    for (; i + 56 < cnt; i += 64) {          // 8 records in flight per half-wave
        int2 r0 = arena[base + i];
        int2 r1 = arena[base + i + 8];
        int2 r2 = arena[base + i + 16];
        int2 r3 = arena[base + i + 24];
        int2 r4 = arena[base + i + 32];
        int2 r5 = arena[base + i + 40];
        int2 r6 = arena[base + i + 48];
        int2 r7 = arena[base + i + 56];
        unsigned h0 = hsrc[(size_t)(r0.x & 0x1FFFF) * 32 + li];
        unsigned h1 = hsrc[(size_t)(r1.x & 0x1FFFF) * 32 + li];
        unsigned h2 = hsrc[(size_t)(r2.x & 0x1FFFF) * 32 + li];
        unsigned h3 = hsrc[(size_t)(r3.x & 0x1FFFF) * 32 + li];
        unsigned h4 = hsrc[(size_t)(r4.x & 0x1FFFF) * 32 + li];
        unsigned h5 = hsrc[(size_t)(r5.x & 0x1FFFF) * 32 + li];
        unsigned h6 = hsrc[(size_t)(r6.x & 0x1FFFF) * 32 + li];
        unsigned h7 = hsrc[(size_t)(r7.x & 0x1FFFF) * 32 + li];
        acc_rec(accs, r0, h0, li);
        acc_rec(accs, r1, h1, li);
        acc_rec(accs, r2, h2, li);
        acc_rec(accs, r3, h3, li);
        acc_rec(accs, r4, h4, li);
        acc_rec(accs, r5, h5, li);
        acc_rec(accs, r6, h6, li);
        acc_rec(accs, r7, h7, li);
    }
    for (; i < cnt; i += 8) {
        const int2 r = arena[base + i];
        const unsigned h = hsrc[(size_t)(r.x & 0x1FFFF) * 32 + li];
        acc_rec(accs, r, h, li);
    }
    __syncthreads();

    if constexpr (FUSE) {
        // h1 = relu(acc*2^-20 + b1) -> bf16, packed (2c,2c+1) into xs for MFMA K-order
        unsigned pk[8];
#pragma unroll
        for (int k = 0; k < 8; ++k) {
            const int i2 = t + k * 256;          // [0,2048): node=i2>>5, colpair=i2&31
            const int node = i2 >> 5, cp = i2 & 31;
            const float f0 = fmaxf((float)accs[node * 64 + 2 * cp]     * FIXINV + bias[2 * cp],     0.f);
            const float f1 = fmaxf((float)accs[node * 64 + 2 * cp + 1] * FIXINV + bias[2 * cp + 1], 0.f);
            pk[k] = pack_bf2(f0, f1);
        }
        __syncthreads();
        unsigned* xs = (unsigned*)accs;          // overlay: [64][36]
#pragma unroll
        for (int k = 0; k < 8; ++k) {
            const int i2 = t + k * 256;
            const int node = i2 >> 5, cp = i2 & 31;
            xs[node * 36 + cp] = pk[k];
        }
        __syncthreads();
        // in-block gemm2: hpre2[64][32 dwords] = h1_tile @ W2, packed (d, d+32)
        const int w = t >> 6, l15 = lane & 15, quad = lane >> 4;
        v4f a4[4];
#pragma unroll
        for (int tt = 0; tt < 4; ++tt) a4[tt] = (v4f){0.f, 0.f, 0.f, 0.f};
#pragma unroll
        for (int k0 = 0; k0 < 64; k0 += 32) {
            const int ku = k0 / 2 + quad * 4;
            const v8s xb = *(const v8s*)&xs[(w * 16 + l15) * 36 + ku];
#pragma unroll
            for (int tt = 0; tt < 4; ++tt) {
                const v8s wa = *(const v8s*)&wsdyn[(16 * tt + l15) * 36 + ku];
                a4[tt] = __builtin_amdgcn_mfma_f32_16x16x32_bf16(wa, xb, a4[tt], 0, 0, 0);
            }
        }
        // repack epilogue via fp32 staging
        __syncthreads();
        float* stg = (float*)accs;               // [64][68]
#pragma unroll
        for (int tt = 0; tt < 4; ++tt)
            *(v4f*)&stg[(w * 16 + l15) * 68 + 16 * tt + 4 * quad] = a4[tt];
        __syncthreads();
        for (int i2 = t; i2 < 2048; i2 += 256) {
            const int nl = i2 >> 5, d = i2 & 31;
            const int ng = b * 64 + nl;
            if (ng < N_NODES)
                ((unsigned*)outp)[(size_t)ng * 32 + d] =
                    pack_bf2(stg[nl * 68 + d], stg[nl * 68 + d + 32]);
        }
    } else {
        // out = relu(acc*2^-20 + b2), fp32 (accs is col-indexed, layout-independent)
        for (int i2 = t; i2 < 2048; i2 += 256) {
            const int node = i2 >> 5, cp = i2 & 31;
            const int ng = b * 64 + node;
            if (ng < N_NODES) {
                float2 o;
                o.x = fmaxf((float)accs[node * 64 + 2 * cp]     * FIXINV + bias[2 * cp],     0.f);
                o.y = fmaxf((float)accs[node * 64 + 2 * cp + 1] * FIXINV + bias[2 * cp + 1], 0.f);
                *(float2*)&((float*)outp)[(size_t)ng * 64 + 2 * cp] = o;
            }
        }
    }
}

extern "C" void kernel_launch(void* const* d_in, const int* in_sizes, int n_in,
                              void* d_out, int out_size, void* d_ws, size_t ws_size,
                              hipStream_t stream) {
    const float* x    = (const float*)d_in[0];          // [100000, 128]
    const int*   eidx = (const int*)d_in[1];            // [2, 1600000]
    const float* mask = (const float*)d_in[2];          // [1600000]
    const float* W1   = (const float*)d_in[3];          // [128, 64]
    const float* b1   = (const float*)d_in[4];          // [64]
    const float* W2   = (const float*)d_in[5];          // [64, 64]
    const float* b2   = (const float*)d_in[6];          // [64]
    float* out = (float*)d_out;                          // [100000, 64]

    const int* src = eidx;
    const int* dst = eidx + N_EDGES;

    // hpre (layer-1 pre-acts, packed bf16 [N][32] dwords = 12.8 MB) lives in d_out,
    // dead before G2 overwrites d_out with the final fp32 output.
    unsigned* hpre = (unsigned*)d_out;

    // workspace: arena 16.0 MB | gcount 0.2 MB | hpre2 12.8 MB
    int2*     arena  = (int2*)d_ws;
    int*      gcount = (int*)(arena + (size_t)NBUCKET * CAP);
    unsigned* hpre2  = (unsigned*)(gcount + NBUCKET * GCSTRIDE);

    const int gemmBlocks = (N_NODES + 63) / 64;          // 1563

    hipMemsetAsync(gcount, 0, NBUCKET * GCSTRIDE * sizeof(int), stream);

    // K1: bucket scatter (blocks 0..390) + layer-1 GEMM tiles (blocks 391..1953)
    k1_sort_gemm<<<NBLK_S + gemmBlocks, 1024, 0, stream>>>(src, dst, mask, x, W1,
                                                           gcount, arena, hpre);

    // G1: gather layer 1 + fused gemm2 -> hpre2 (packed bf16)
    gather_fuse<true><<<NBUCKET, 256, 64 * 36 * 4, stream>>>(hpre, arena, gcount,
                                                             b1, W2, hpre2);
    // G2: gather layer 2 -> out (fp32)
    gather_fuse<false><<<NBUCKET, 256, 0, stream>>>(hpre2, arena, gcount,
                                                    b2, nullptr, out);
}

// Round 7
// 221.611 us; speedup vs baseline: 6.0293x; 1.1058x over previous
//
#include <hip/hip_runtime.h>
#include <hip/hip_bf16.h>

#define N_NODES 100000
#define N_EDGES 1600000
#define NB_C 391                    // coarse buckets (dst >> 8)
#define NB_F 1563                   // fine buckets (dst >> 6) = gather blocks
#define NBLK_S 391                  // sort chunks: ceil(1.6M / 4096)
#define CHUNK_E 4096                // one int4 (4 edges) per thread at 1024 threads
#define CAPC 4608                   // coarse arena capacity (mean 4092 + 8 sigma)
#define QCAP 1280                   // fine LDS queue cap (mean 1024 + 8 sigma), mult of 128
#define GCSTRIDE 32                 // one counter per 128B line
#define FIXSCALE 1048576.0f         // 2^20 fixed-point scale for LDS int accumulation
#define FIXINV   (1.0f / 1048576.0f)

// hpre/hpre2 packing: dword d of a row = bf16 pair (col d, col d+32).
// Gather quarter q reads dwords a=(li2+8q)&31 and a+16 -> ds_add banks get
// exactly 2 lanes/bank (free per m136).

typedef short v8s __attribute__((ext_vector_type(8)));
typedef float v4f __attribute__((ext_vector_type(4)));

static __device__ __forceinline__ unsigned pack_bf2(float a, float b) {
    __hip_bfloat162 p = __float22bfloat162_rn(make_float2(a, b));
    return *reinterpret_cast<unsigned*>(&p);
}
static __device__ __forceinline__ float2 bf2_to_f2(unsigned u) {
    __hip_bfloat162 p = *reinterpret_cast<__hip_bfloat162*>(&u);
    return __bfloat1622float2(p);
}

// ---------- K1 (1024 thr): blocks [0,NBLK_S) = coarse bucket scatter; rest = layer-1 GEMM ----------
__global__ __launch_bounds__(1024) void k1_sort_gemm(const int* __restrict__ src,
                                                     const int* __restrict__ dst,
                                                     const float* __restrict__ wgt,
                                                     const float* __restrict__ x,
                                                     const float* __restrict__ W1,
                                                     int* __restrict__ gcount,
                                                     int2* __restrict__ arena,
                                                     unsigned* __restrict__ hpre) {
    __shared__ __align__(16) int smem[13976];   // 55.9 KB union (sort view / gemm view)
    const int b = blockIdx.x;
    const int t = threadIdx.x;

    if (b >= NBLK_S) {
        // ---- layer-1 GEMM tile: hpre[64 nodes][32 dwords] = x_tile @ W1 (packed d,d+32) ----
        unsigned* xs = (unsigned*)smem;              // [64][68]
        unsigned* ws = (unsigned*)smem + 64 * 68;    // [64][68]
        const int tile = b - NBLK_S;
        const int row0 = tile * 64;
        {   // stage W1: fp32 [128][64] -> ws[col] bf16 at short index k (transpose)
            const float2* g2 = (const float2*)W1;
            for (int i = t; i < 64 * 128 / 2; i += 1024) {
                const float2 v = g2[i];
                const int k = (2 * i) >> 6;
                const int c = (2 * i) & 63;
                ((short*)&ws[c * 68])[k]       = (short)(pack_bf2(v.x, 0.f) & 0xFFFF);
                ((short*)&ws[(c + 1) * 68])[k] = (short)(pack_bf2(v.y, 0.f) & 0xFFFF);
            }
        }
        {   // stage x tile: fp32 -> bf16 packed
            const float4* g = (const float4*)x;
            for (int i = t; i < 64 * 32; i += 1024) {
                const int r = i >> 5, cu = i & 31;
                const int row = row0 + r;
                uint2 v = make_uint2(0u, 0u);
                if (row < N_NODES) {
                    float4 f = g[(size_t)row * 32 + cu];
                    v.x = pack_bf2(f.x, f.y);
                    v.y = pack_bf2(f.z, f.w);
                }
                *(uint2*)&xs[r * 68 + 2 * cu] = v;
            }
        }
        __syncthreads();
        const int w = t >> 6, lane = t & 63;
        const int l15 = lane & 15, quad = lane >> 4;
        const int a  = w & 3;      // out-col group (16 cols)
        const int g_ = w >> 2;     // node group (16 nodes)
        v4f acc = (v4f){0.f, 0.f, 0.f, 0.f};
#pragma unroll
        for (int k0 = 0; k0 < 128; k0 += 32) {
            const int ku = k0 / 2 + quad * 4;
            const v8s xb = *(const v8s*)&xs[(g_ * 16 + l15) * 68 + ku];
            const v8s wa = *(const v8s*)&ws[(16 * a + l15) * 68 + ku];
            acc = __builtin_amdgcn_mfma_f32_16x16x32_bf16(wa, xb, acc, 0, 0, 0);
        }
        // repack epilogue: stage fp32 tile in LDS, emit (d, d+32) bf16 pairs
        __syncthreads();
        float* stg = (float*)smem;                    // [64][68] fp32
        *(v4f*)&stg[(g_ * 16 + l15) * 68 + 16 * a + 4 * quad] = acc;
        __syncthreads();
        for (int i2 = t; i2 < 2048; i2 += 1024) {
            const int nl = i2 >> 5, d = i2 & 31;
            const int row = row0 + nl;
            if (row < N_NODES)
                hpre[(size_t)row * 32 + d] = pack_bf2(stg[nl * 68 + d], stg[nl * 68 + d + 32]);
        }
        return;
    }

    // ---- sort path: block-local counting sort of 4096 edges into 391 coarse buckets ----
    int*  hist  = smem;              // [391]
    int*  lcur  = smem + 391;        // [391]
    int*  tgb   = smem + 782;        // [391]
    int*  pairs = smem + 1173;       // [512] scan
    int*  tg    = smem + 1685;       // [4096]
    int2* ord   = (int2*)(smem + 5782); // [4096] (8B aligned)

    for (int i = t; i < NB_C; i += 1024) hist[i] = 0;
    __syncthreads();

    const int e0 = b * CHUNK_E;
    const int n = min(CHUNK_E, N_EDGES - e0);   // 4096, or 2560 for last block
    const int nI4 = n >> 2;
    const bool act = t < nI4;
    int4 sv, dv; float4 wv;
    if (act) {
        sv = ((const int4*)(src + e0))[t];
        dv = ((const int4*)(dst + e0))[t];
        wv = ((const float4*)(wgt + e0))[t];
        atomicAdd(&hist[dv.x >> 8], 1);
        atomicAdd(&hist[dv.y >> 8], 1);
        atomicAdd(&hist[dv.z >> 8], 1);
        atomicAdd(&hist[dv.w >> 8], 1);
    }
    __syncthreads();
    // Hillis-Steele inclusive scan over 512 (covers 391 bins)
    if (t < 512) pairs[t] = (t < NB_C) ? hist[t] : 0;
    __syncthreads();
    for (int off = 1; off < 512; off <<= 1) {
        int u = 0;
        if (t < 512 && t >= off) u = pairs[t - off];
        __syncthreads();
        if (t < 512) pairs[t] += u;
        __syncthreads();
    }
    if (t < NB_C) lcur[t] = pairs[t] - hist[t];     // exclusive
    __syncthreads();
    for (int i = t; i < NB_C; i += 1024) {
        const int hv = hist[i];
        const int lb = lcur[i];
        const int grsv = (hv > 0) ? atomicAdd(&gcount[i * GCSTRIDE], hv) : 0;
        tgb[i] = i * CAPC + grsv - lb;
    }
    __syncthreads();
    if (act) {
        {
            const int bk = dv.x >> 8;
            const int lp = atomicAdd(&lcur[bk], 1);
            ord[lp] = make_int2(sv.x | ((dv.x & 255) << 17), __float_as_int(wv.x));
            tg[lp] = tgb[bk] + lp;
        }
        {
            const int bk = dv.y >> 8;
            const int lp = atomicAdd(&lcur[bk], 1);
            ord[lp] = make_int2(sv.y | ((dv.y & 255) << 17), __float_as_int(wv.y));
            tg[lp] = tgb[bk] + lp;
        }
        {
            const int bk = dv.z >> 8;
            const int lp = atomicAdd(&lcur[bk], 1);
            ord[lp] = make_int2(sv.z | ((dv.z & 255) << 17), __float_as_int(wv.z));
            tg[lp] = tgb[bk] + lp;
        }
        {
            const int bk = dv.w >> 8;
            const int lp = atomicAdd(&lcur[bk], 1);
            ord[lp] = make_int2(sv.w | ((dv.w & 255) << 17), __float_as_int(wv.w));
            tg[lp] = tgb[bk] + lp;
        }
    }
    __syncthreads();
    // coalesced write-out: runs of ~10.5 records per bucket per chunk
    for (int i = t; i < n; i += 1024)
        arena[tg[i]] = ord[i];
}

// ---------- G: fine-bucket gather. Compacts its quarter of a coarse bucket into an LDS
// queue, then quarter-wave (16 lanes/record) accumulation with native ds_add.
// FUSE=true adds in-block gemm2 (h1 @ W2) and writes packed bf16; else fp32 out. ----------
template<bool FUSE>
__global__ __launch_bounds__(256) void gather_fuse(const unsigned* __restrict__ hsrc, // packed [N][32]
                                                   const int2* __restrict__ arena,
                                                   const int* __restrict__ gcount,
                                                   const float* __restrict__ bias,
                                                   const float* __restrict__ W2,
                                                   void* __restrict__ outp) {
    __shared__ int accs[64 * 68];            // fixed-point acc; also fp32 staging [64][68]
    __shared__ int2 qrec[QCAP];              // 10.2 KB compacted records
    __shared__ int qn_s;
    extern __shared__ unsigned wsdyn[];      // [64*36] bf16 W2^T (FUSE only)
    const int t = threadIdx.x;

    // bijective XCD swizzle (nwg=1563: q=195, r=3) so 4 sibling blocks share an L2
    const int orig = blockIdx.x;
    const int xcd = orig & 7, idx = orig >> 3;
    const int b = (xcd < 3 ? xcd * 196 : 3 * 196 + (xcd - 3) * 195) + idx;

    const int cb = b >> 2;                   // coarse bucket
    const int sub = b & 3;                   // which fine quarter
    for (int i = t; i < 4096; i += 256) accs[i] = 0;
    if (t == 0) qn_s = 0;
    if constexpr (FUSE) {
        const float2* g2 = (const float2*)W2;
        for (int i = t; i < 2048; i += 256) {
            const float2 v = g2[i];
            const int k = (2 * i) >> 6;
            const int c = (2 * i) & 63;
            ((short*)&wsdyn[c * 36])[k]       = (short)(pack_bf2(v.x, 0.f) & 0xFFFF);
            ((short*)&wsdyn[(c + 1) * 36])[k] = (short)(pack_bf2(v.y, 0.f) & 0xFFFF);
        }
    }
    __syncthreads();

    // compact my sub-bucket's records (coalesced coarse read, LDS append)
    const int cntc = min(gcount[cb * GCSTRIDE], CAPC);
    const size_t cbase = (size_t)cb * CAPC;
    for (int i = t; i < cntc; i += 256) {
        const int2 r = arena[cbase + i];
        if (((r.x >> 23) & 3) == sub) {
            const int pos = atomicAdd(&qn_s, 1);
            if (pos < QCAP) qrec[pos] = r;
        }
    }
    __syncthreads();
    const int qn = min(qn_s, QCAP);
    const int npad = (qn + 127) & ~127;      // pad to multiple of 128 with zero-weight recs
    for (int i = qn + t; i < npad; i += 256) qrec[i] = make_int2(0, 0);
    __syncthreads();

    // quarter-wave gather: 16 streams x 8-deep; lane loads dwords a and a+16 (rotated)
    const int li2 = t & 15;
    const int s   = t >> 4;                  // stream 0..15
    const int qw  = s & 3;
    const int da  = (li2 + 8 * qw) & 31;
    const int db  = (da + 16) & 31;
    for (int ib = s; ib < npad; ib += 128) {
        int2 r[8];
#pragma unroll
        for (int j = 0; j < 8; ++j) r[j] = qrec[ib + 16 * j];
        unsigned ha[8], hb[8];
#pragma unroll
        for (int j = 0; j < 8; ++j) {
            const unsigned* row = hsrc + (size_t)(r[j].x & 0x1FFFF) * 32;
            ha[j] = row[da];
            hb[j] = row[db];
        }
#pragma unroll
        for (int j = 0; j < 8; ++j) {
            const int dl = (r[j].x >> 17) & 63;
            const float wsf = __int_as_float(r[j].y) * FIXSCALE;
            const float2 fa = bf2_to_f2(ha[j]);   // cols (da, da+32)
            const float2 fb = bf2_to_f2(hb[j]);   // cols (db, db+32)
            atomicAdd(&accs[dl * 64 + da],      (int)(wsf * fa.x));
            atomicAdd(&accs[dl * 64 + da + 32], (int)(wsf * fa.y));
            atomicAdd(&accs[dl * 64 + db],      (int)(wsf * fb.x));
            atomicAdd(&accs[dl * 64 + db + 32], (int)(wsf * fb.y));
        }
    }
    __syncthreads();

    const int lane = t & 63;
    if constexpr (FUSE) {
        // h1 = relu(acc*2^-20 + b1) -> bf16 (2c,2c+1) into xs for MFMA K-order
        unsigned pk[8];
#pragma unroll
        for (int k = 0; k < 8; ++k) {
            const int i2 = t + k * 256;          // node=i2>>5, colpair=i2&31
            const int node = i2 >> 5, cp = i2 & 31;
            const float f0 = fmaxf((float)accs[node * 64 + 2 * cp]     * FIXINV + bias[2 * cp],     0.f);
            const float f1 = fmaxf((float)accs[node * 64 + 2 * cp + 1] * FIXINV + bias[2 * cp + 1], 0.f);
            pk[k] = pack_bf2(f0, f1);
        }
        __syncthreads();
        unsigned* xs = (unsigned*)accs;          // overlay: [64][36]
#pragma unroll
        for (int k = 0; k < 8; ++k) {
            const int i2 = t + k * 256;
            const int node = i2 >> 5, cp = i2 & 31;
            xs[node * 36 + cp] = pk[k];
        }
        __syncthreads();
        // in-block gemm2: hpre2[64][32 dwords] = h1_tile @ W2, packed (d, d+32)
        const int w = t >> 6, l15 = lane & 15, quad = lane >> 4;
        v4f a4[4];
#pragma unroll
        for (int tt = 0; tt < 4; ++tt) a4[tt] = (v4f){0.f, 0.f, 0.f, 0.f};
#pragma unroll
        for (int k0 = 0; k0 < 64; k0 += 32) {
            const int ku = k0 / 2 + quad * 4;
            const v8s xb = *(const v8s*)&xs[(w * 16 + l15) * 36 + ku];
#pragma unroll
            for (int tt = 0; tt < 4; ++tt) {
                const v8s wa = *(const v8s*)&wsdyn[(16 * tt + l15) * 36 + ku];
                a4[tt] = __builtin_amdgcn_mfma_f32_16x16x32_bf16(wa, xb, a4[tt], 0, 0, 0);
            }
        }
        __syncthreads();
        float* stg = (float*)accs;               // [64][68]
#pragma unroll
        for (int tt = 0; tt < 4; ++tt)
            *(v4f*)&stg[(w * 16 + l15) * 68 + 16 * tt + 4 * quad] = a4[tt];
        __syncthreads();
        for (int i2 = t; i2 < 2048; i2 += 256) {
            const int nl = i2 >> 5, d = i2 & 31;
            const int ng = b * 64 + nl;
            if (ng < N_NODES)
                ((unsigned*)outp)[(size_t)ng * 32 + d] =
                    pack_bf2(stg[nl * 68 + d], stg[nl * 68 + d + 32]);
        }
    } else {
        // out = relu(acc*2^-20 + b2), fp32
        for (int i2 = t; i2 < 2048; i2 += 256) {
            const int node = i2 >> 5, cp = i2 & 31;
            const int ng = b * 64 + node;
            if (ng < N_NODES) {
                float2 o;
                o.x = fmaxf((float)accs[node * 64 + 2 * cp]     * FIXINV + bias[2 * cp],     0.f);
                o.y = fmaxf((float)accs[node * 64 + 2 * cp + 1] * FIXINV + bias[2 * cp + 1], 0.f);
                *(float2*)&((float*)outp)[(size_t)ng * 64 + 2 * cp] = o;
            }
        }
    }
}

extern "C" void kernel_launch(void* const* d_in, const int* in_sizes, int n_in,
                              void* d_out, int out_size, void* d_ws, size_t ws_size,
                              hipStream_t stream) {
    const float* x    = (const float*)d_in[0];          // [100000, 128]
    const int*   eidx = (const int*)d_in[1];            // [2, 1600000]
    const float* mask = (const float*)d_in[2];          // [1600000]
    const float* W1   = (const float*)d_in[3];          // [128, 64]
    const float* b1   = (const float*)d_in[4];          // [64]
    const float* W2   = (const float*)d_in[5];          // [64, 64]
    const float* b2   = (const float*)d_in[6];          // [64]
    float* out = (float*)d_out;                          // [100000, 64]

    const int* src = eidx;
    const int* dst = eidx + N_EDGES;

    // hpre (layer-1 pre-acts, packed bf16 [N][32] dwords = 12.8 MB) lives in d_out,
    // dead before G2 overwrites d_out with the final fp32 output.
    unsigned* hpre = (unsigned*)d_out;

    // workspace: coarse arena 14.4 MB | gcount 50 KB | hpre2 12.8 MB
    int2*     arena  = (int2*)d_ws;
    int*      gcount = (int*)(arena + (size_t)NB_C * CAPC);
    unsigned* hpre2  = (unsigned*)(gcount + NB_C * GCSTRIDE);

    const int gemmBlocks = (N_NODES + 63) / 64;          // 1563

    hipMemsetAsync(gcount, 0, NB_C * GCSTRIDE * sizeof(int), stream);

    // K1: coarse bucket scatter (blocks 0..390) + layer-1 GEMM tiles (blocks 391..1953)
    k1_sort_gemm<<<NBLK_S + gemmBlocks, 1024, 0, stream>>>(src, dst, mask, x, W1,
                                                           gcount, arena, hpre);

    // G1: gather layer 1 + fused gemm2 -> hpre2 (packed bf16)
    gather_fuse<true><<<NB_F, 256, 64 * 36 * 4, stream>>>(hpre, arena, gcount,
                                                          b1, W2, hpre2);
    // G2: gather layer 2 -> out (fp32)
    gather_fuse<false><<<NB_F, 256, 0, stream>>>(hpre2, arena, gcount,
                                                 b2, nullptr, out);
}